// Round 18
// baseline (103.711 us; speedup 1.0000x reference)
//
#include <hip/hip_runtime.h>
#include <hip/hip_fp16.h>
#include <math.h>

#define HW     16384
#define IMG_H  128
#define IMG_W  128

typedef _Float16 f16x2 __attribute__((ext_vector_type(2)));
typedef __fp16 fp16v2 __attribute__((ext_vector_type(2)));
typedef _Float16 f16x4 __attribute__((ext_vector_type(4)));
typedef float f32x4 __attribute__((ext_vector_type(4)));

// ws layout in float units
#define OFF_T2    ((size_t)0)          // uint2[8*32*16384] (off-pair, m-pair) 33.5MB
#define OFF_XT    ((size_t)8388608)    // __half[32*16384*16] channel-last x, 16.8MB
#define OFF_WT    ((size_t)12582912)   // float[6912]  pw weights c-major
#define OFF_PART  ((size_t)12599040)   // float[16384] per-block GN partials
#define OFF_WB    ((size_t)19711744)   // uint2[4*9*64] f16 B-fragments (gather MFMA)
#define OFF_WDW2  ((size_t)19716352)   // uint[64*2*7*4] packed half2 dw weights
#define OFF_WBO   ((size_t)19719936)   // uint2[8*4*8*64]  pw-GEMM off B-frags
#define OFF_WBM   ((size_t)19752704)   // uint2[8*4*4*64]  pw-GEMM mask B-frags
#define OFF_DC    ((size_t)19769088)   // float[8*108]  GN-folded pw bias
// end = 19769952 floats = 79.1 MB

// ---------------------------------------------------------------------------
// k_prep: wT[c][108] (pw weights c-major), wb (gather MFMA B-frags),
// wdw2: packed half2 dw-weight pairs.
__global__ void k_prep(const float* __restrict__ wpw_off,
                       const float* __restrict__ wpw_m,
                       const float* __restrict__ wdef,
                       const float* __restrict__ wdwo,
                       const float* __restrict__ wdwm,
                       float* __restrict__ ws) {
    int i = blockIdx.x * 256 + threadIdx.x;
    if (i < 6912) {
        int c = i / 108, o = i % 108;
        ws[OFF_WT + i] = (o < 72) ? wpw_off[o * 64 + c] : wpw_m[(o - 72) * 64 + c];
    } else if (i < 9216) {
        int j = i - 6912;               // (g*9+tap)*64 + lane
        int lane = j & 63;
        int gt = j >> 6;
        int tap = gt % 9, g = gt / 9;
        int oc = lane & 15, qh = lane >> 4;
        union { ushort h[4]; uint2 u; } pk;
#pragma unroll
        for (int jj = 0; jj < 4; ++jj) {
            float wv = wdef[((g * 16 + oc) * 16 + (4 * qh + jj)) * 9 + tap];
            pk.h[jj] = __half_as_ushort(__float2half(wv));
        }
        ((uint2*)(ws + OFF_WB))[j] = pk.u;
    } else if (i < 12800) {
        int j = i - 9216;               // ((c*2+conv)*7+dy)*4 + q
        int q = j & 3;
        int r = j >> 2;
        int dy = r % 7;
        int cv = (r / 7) & 1;
        int c = r / 14;
        const float* src = cv ? wdwm : wdwo;
        int dx0 = q * 2;
        float w0 = src[c * 49 + dy * 7 + dx0];
        float w1 = (dx0 + 1 < 7) ? src[c * 49 + dy * 7 + dx0 + 1] : 0.f;
        union { __half h[2]; uint u; } pk;
        pk.h[0] = __float2half(w0);
        pk.h[1] = __float2half(w1);
        ((uint*)(ws + OFF_WDW2))[j] = pk.u;
    }
}

// ---------------------------------------------------------------------------
// k_trans: x[B,C,H,W] -> xT[bg][p][16] fp16
__global__ __launch_bounds__(256) void k_trans(const float* __restrict__ x,
                                               __half* __restrict__ xT) {
    int n = blockIdx.x * 256 + threadIdx.x;     // n = bg*HW + p
    int p = n & (HW - 1);
    int bg = n >> 14;
    const float* src = x + (size_t)bg * 16 * HW + p;
    union { __half2 h2[8]; uint4 u[2]; } pk;
#pragma unroll
    for (int i = 0; i < 8; ++i) {
        float a = src[(size_t)(2 * i) * HW];
        float bq = src[(size_t)(2 * i + 1) * HW];
        pk.h2[i] = __halves2half2(__float2half(a), __float2half(bq));
    }
    uint4* dst = (uint4*)(xT + (size_t)n * 16);
    dst[0] = pk.u[0];
    dst[1] = pk.u[1];
}

// ---------------------------------------------------------------------------
// k_dw: both depthwise 7x7 convs via v_dot2_f32_f16; 2 channels per thread;
// writes channel-PAIRED layout t2p[b][c2][p]. Zero padding.
__global__ __launch_bounds__(256) void k_dw(const float* __restrict__ x,
                                            const float* __restrict__ bdwo,
                                            const float* __restrict__ bdwm,
                                            const uint* __restrict__ wdw2,
                                            uint2* __restrict__ t2p,
                                            float* __restrict__ partial) {
    int bid = blockIdx.x;
    int b = bid >> 9;                       // 32 c2 x 16 stripes per b
    int c2 = (bid >> 4) & 31;
    int stripe = (bid & 15) * 8;
    int t = threadIdx.x;
    int cb = t & 31;                        // 4-col block
    int row = stripe + (t >> 5);
    int c0 = c2 * 2;

    float vo[2][4], vm[2][4];
    float s1o = 0.f, s2o = 0.f, s1m = 0.f, s2m = 0.f;
    union CV { fp16v2 v; f16x2 h; };
    union WU { uint u; f16x2 h; };

#pragma unroll
    for (int ch = 0; ch < 2; ++ch) {
        int c = c0 + ch;
        const float4* pl = (const float4*)(x + ((size_t)(b * 64 + c)) * HW);
        const uint* wp = wdw2 + c * 56;
        float acco[4] = {0.f, 0.f, 0.f, 0.f};
        float accm[4] = {0.f, 0.f, 0.f, 0.f};
#pragma unroll
        for (int dy = 0; dy < 7; ++dy) {
            int iy = row - 3 + dy;
            if (iy >= 0 && iy < IMG_H) {
                const float4* prow = pl + iy * 32;
                float4 f4 = prow[cb];
                float4 f4m = prow[cb == 0 ? 0 : cb - 1];
                float4 f4p = prow[cb == 31 ? 31 : cb + 1];
                bool le = (cb == 0), re = (cb == 31);
                float v[11];
                v[0] = le ? 0.f : f4m.y;
                v[1] = le ? 0.f : f4m.z;
                v[2] = le ? 0.f : f4m.w;
                v[3] = f4.x; v[4] = f4.y; v[5] = f4.z; v[6] = f4.w;
                v[7] = re ? 0.f : f4p.x;
                v[8] = re ? 0.f : f4p.y;
                v[9] = re ? 0.f : f4p.z;
                v[10] = re ? 0.f : f4p.w;
                f16x2 hp[10];
#pragma unroll
                for (int d = 0; d < 10; ++d) {
                    CV cv;
                    cv.v = __builtin_amdgcn_cvt_pkrtz(v[d], v[d + 1]);
                    hp[d] = cv.h;
                }
#pragma unroll
                for (int cc = 0; cc < 4; ++cc) {
                    WU w0, w1, w2, w3, u0, u1, u2, u3;
                    w0.u = wp[dy * 4 + 0]; w1.u = wp[dy * 4 + 1];
                    w2.u = wp[dy * 4 + 2]; w3.u = wp[dy * 4 + 3];
                    u0.u = wp[28 + dy * 4 + 0]; u1.u = wp[28 + dy * 4 + 1];
                    u2.u = wp[28 + dy * 4 + 2]; u3.u = wp[28 + dy * 4 + 3];
                    float ao = acco[cc], am = accm[cc];
                    ao = __builtin_amdgcn_fdot2(hp[cc],     w0.h, ao, false);
                    ao = __builtin_amdgcn_fdot2(hp[cc + 2], w1.h, ao, false);
                    ao = __builtin_amdgcn_fdot2(hp[cc + 4], w2.h, ao, false);
                    ao = __builtin_amdgcn_fdot2(hp[cc + 6], w3.h, ao, false);
                    am = __builtin_amdgcn_fdot2(hp[cc],     u0.h, am, false);
                    am = __builtin_amdgcn_fdot2(hp[cc + 2], u1.h, am, false);
                    am = __builtin_amdgcn_fdot2(hp[cc + 4], u2.h, am, false);
                    am = __builtin_amdgcn_fdot2(hp[cc + 6], u3.h, am, false);
                    acco[cc] = ao; accm[cc] = am;
                }
            }
        }
        float bo = bdwo[c], bm = bdwm[c];
#pragma unroll
        for (int cc = 0; cc < 4; ++cc) {
            float o_ = acco[cc] + bo, m_ = accm[cc] + bm;
            vo[ch][cc] = o_; vm[ch][cc] = m_;
            s1o += o_; s2o += o_ * o_; s1m += m_; s2m += m_ * m_;
        }
    }

    union { uint2 u2[4]; uint4 u4[2]; } ot;
#pragma unroll
    for (int cc = 0; cc < 4; ++cc) {
        ot.u2[cc].x = (uint)__half_as_ushort(__float2half(vo[0][cc])) |
                      ((uint)__half_as_ushort(__float2half(vo[1][cc])) << 16);
        ot.u2[cc].y = (uint)__half_as_ushort(__float2half(vm[0][cc])) |
                      ((uint)__half_as_ushort(__float2half(vm[1][cc])) << 16);
    }
    uint4* dst = (uint4*)(t2p + ((size_t)(b * 32 + c2) * HW + row * IMG_W + cb * 4));
    dst[0] = ot.u4[0];
    dst[1] = ot.u4[1];

#pragma unroll
    for (int d = 32; d; d >>= 1) {
        s1o += __shfl_down(s1o, d);
        s2o += __shfl_down(s2o, d);
        s1m += __shfl_down(s1m, d);
        s2m += __shfl_down(s2m, d);
    }
    __shared__ float red[4][4];
    if ((t & 63) == 0) {
        int w = t >> 6;
        red[w][0] = s1o; red[w][1] = s2o; red[w][2] = s1m; red[w][3] = s2m;
    }
    __syncthreads();
    if (t < 4) {
        float v = red[0][t] + red[1][t] + red[2][t] + red[3][t];
        partial[(size_t)bid * 4 + t] = v;
    }
}

// ---------------------------------------------------------------------------
// k_finfold: one block per sample. Phase 1: reduce partials -> GN affine in
// LDS. Phase 2: emit GN-folded pw-GEMM MFMA B-fragments + dconst.
__global__ __launch_bounds__(256) void k_finfold(const float* __restrict__ partial,
                      const float* __restrict__ gog, const float* __restrict__ gob,
                      const float* __restrict__ gmg, const float* __restrict__ gmb,
                      const float* __restrict__ wT,
                      const float* __restrict__ bpo,
                      const float* __restrict__ bpm,
                      uint2* __restrict__ wbo,
                      uint2* __restrict__ wbm,
                      float* __restrict__ dconst) {
    __shared__ float adsh[256];
    int b = blockIdx.x, t = threadIdx.x;
    {
        const float4* pp = (const float4*)partial + (size_t)b * 512;
        float4 s = make_float4(0.f, 0.f, 0.f, 0.f);
#pragma unroll
        for (int i = 0; i < 2; ++i) {
            float4 v = pp[t + i * 256];
            s.x += v.x; s.y += v.y; s.z += v.z; s.w += v.w;
        }
#pragma unroll
        for (int d = 32; d; d >>= 1) {
            s.x += __shfl_down(s.x, d);
            s.y += __shfl_down(s.y, d);
            s.z += __shfl_down(s.z, d);
            s.w += __shfl_down(s.w, d);
        }
        __shared__ float red[4][4];
        if ((t & 63) == 0) {
            int w = t >> 6;
            red[w][0] = s.x; red[w][1] = s.y; red[w][2] = s.z; red[w][3] = s.w;
        }
        __syncthreads();
        if (t < 64) {
            float s1o = red[0][0] + red[1][0] + red[2][0] + red[3][0];
            float s2o = red[0][1] + red[1][1] + red[2][1] + red[3][1];
            float s1m = red[0][2] + red[1][2] + red[2][2] + red[3][2];
            float s2m = red[0][3] + red[1][3] + red[2][3] + red[3][3];
            int c = t;
            const float invN = 1.f / 1048576.f;
            float m_o = s1o * invN;
            float v_o = s2o * invN - m_o * m_o;
            float i_o = rsqrtf(v_o + 1e-5f);
            float m_m = s1m * invN;
            float v_m = s2m * invN - m_m * m_m;
            float i_m = rsqrtf(v_m + 1e-5f);
            adsh[c * 4 + 0] = i_o * gog[c];
            adsh[c * 4 + 1] = gob[c] - m_o * (i_o * gog[c]);
            adsh[c * 4 + 2] = i_m * gmg[c];
            adsh[c * 4 + 3] = gmb[c] - m_m * (i_m * gmg[c]);
        }
        __syncthreads();
    }
    // ---- fold phase (reads adsh) ----
    for (int i = t; i < 2048; i += 256) {       // off frags
        int lane = i & 63;
        int f = i >> 6;
        int g = f >> 3, kk = (f >> 1) & 3, nf = f & 1;
        int n = lane & 15, q = lane >> 4;
        int out = nf * 16 + n;
        union { ushort h[4]; uint2 u; } pk;
#pragma unroll
        for (int jj = 0; jj < 4; ++jj) {
            int ch = kk * 16 + 4 * q + jj;
            float w = (out < 18) ? adsh[ch * 4 + 0] * wT[ch * 108 + g * 18 + out] : 0.f;
            pk.h[jj] = __half_as_ushort(__float2half(w));
        }
        wbo[((size_t)(b * 4) + g) * 8 * 64 + (size_t)(kk * 2 + nf) * 64 + lane] = pk.u;
    }
    for (int i = t; i < 1024; i += 256) {       // mask frags
        int lane = i & 63;
        int f = i >> 6;
        int g = f >> 2, kk = f & 3;
        int n = lane & 15, q = lane >> 4;
        union { ushort h[4]; uint2 u; } pk;
#pragma unroll
        for (int jj = 0; jj < 4; ++jj) {
            int ch = kk * 16 + 4 * q + jj;
            float w = (n < 9) ? adsh[ch * 4 + 2] * wT[ch * 108 + 72 + g * 9 + n] : 0.f;
            pk.h[jj] = __half_as_ushort(__float2half(w));
        }
        wbm[((size_t)(b * 4) + g) * 4 * 64 + (size_t)kk * 64 + lane] = pk.u;
    }
    if (t < 108) {
        float s = (t < 72) ? bpo[t] : bpm[t - 72];
        for (int c = 0; c < 64; ++c) {
            float d = (t < 72) ? adsh[c * 4 + 1] : adsh[c * 4 + 3];
            s = fmaf(d, wT[c * 108 + t], s);
        }
        dconst[b * 108 + t] = s;
    }
}

// ---------------------------------------------------------------------------
// k_gthf: FUSED MFMA pw-GEMM + softmax + LDS-staged bilinear gather + MFMA.
// R18: xs staging split (load regs early, LDS-write after GEMM), 2-stage
// t2p pipeline, gather B-frags loaded late.
__global__ __launch_bounds__(256, 4) void k_gthf(const uint2* __restrict__ t2p,
                                                 const uint2* __restrict__ wbo,
                                                 const uint2* __restrict__ wbm,
                                                 const float* __restrict__ dconst,
                                                 const __half* __restrict__ xT,
                                                 const uint2* __restrict__ wb,
                                                 const float* __restrict__ bias,
                                                 float* __restrict__ out) {
    __shared__ union SMem {
        struct {
            uint4 xsA[506];     // 22 rows x stride 23, ch 0-7
            uint4 xsB[506];     // ch 8-15
            uint  slab[5120];   // 4 waves x [64 px][20 uint] (A/D/shv alias)
        } s;
        float shout[4864];      // 256 px x stride 19 (aliased, post-barrier)
    } sm;

    int tid = threadIdx.x;
    int bid = blockIdx.x;
    int bg = bid >> 6;                      // slice-major: g-variants same XCD
    int tile = bid & 63;
    int tr = tile >> 3, tc = tile & 7;
    int r0 = tr * 16, c0 = tc * 16;
    int g = bg & 3, b = bg >> 2;
    int wr0 = r0 - 3, wc0 = c0 - 3;

    const __half* xg = xT + (size_t)bg * HW * 16;

    // ---- async-stage split: issue xs loads into registers ----
    int sidx[2];
    uint4 sA[2], sB[2];
#pragma unroll
    for (int it = 0; it < 2; ++it) {
        int idx = tid + it * 256;
        sidx[it] = -1;
        if (idx < 484) {
            int ly = idx / 22, lx = idx - ly * 22;
            int sr = wr0 + ly; sr = sr < 0 ? 0 : (sr > 127 ? 127 : sr);
            int sc = wc0 + lx; sc = sc < 0 ? 0 : (sc > 127 ? 127 : sc);
            const uint4* src = (const uint4*)(xg + (size_t)(sr * IMG_W + sc) * 16);
            sA[it] = src[0];
            sB[it] = src[1];
            sidx[it] = ly * 23 + lx;
        }
    }

    int row = r0 + (tid >> 4), col = c0 + (tid & 15);
    int p = row * IMG_W + col;
    int lane = tid & 63, wv = tid >> 6;
    int m_idx = lane & 15, q_idx = lane >> 4;

    union BU { uint2 u; f16x4 h; };

    // ---- pw-GEMM B-fragments (wave-invariant) ----
    const uint2* wboP = wbo + ((size_t)(b * 4) + g) * 8 * 64 + lane;
    const uint2* wbmP = wbm + ((size_t)(b * 4) + g) * 4 * 64 + lane;
    f16x4 bO[8], bM[4];
#pragma unroll
    for (int i = 0; i < 8; ++i) { BU t; t.u = wboP[i * 64]; bO[i] = t.h; }
#pragma unroll
    for (int i = 0; i < 4; ++i) { BU t; t.u = wbmP[i * 64]; bM[i] = t.h; }

    // ---- MFMA pw-GEMM: A via per-wave LDS slab, 2-stage t2p pipeline ----
    uint* aslab = sm.s.slab + wv * 1280;        // [64 px][20 uint]
    const uint2* tp = t2p + (size_t)b * 32 * HW + p;

    f32x4 accO0[4], accO1[4], accM[4];
#pragma unroll
    for (int s = 0; s < 4; ++s) {
        accO0[s] = (f32x4){0.f, 0.f, 0.f, 0.f};
        accO1[s] = (f32x4){0.f, 0.f, 0.f, 0.f};
        accM[s]  = (f32x4){0.f, 0.f, 0.f, 0.f};
    }

    uint2 cur[8], nxt[8];
#pragma unroll
    for (int j = 0; j < 8; ++j) cur[j] = tp[(size_t)j * HW];

#pragma unroll
    for (int kk = 0; kk < 4; ++kk) {
        if (kk < 3) {
#pragma unroll
            for (int j = 0; j < 8; ++j) nxt[j] = tp[(size_t)((kk + 1) * 8 + j) * HW];
        }
        uint* rowp = aslab + lane * 20;
        ((uint4*)rowp)[0] = make_uint4(cur[0].x, cur[1].x, cur[2].x, cur[3].x);
        ((uint4*)rowp)[1] = make_uint4(cur[4].x, cur[5].x, cur[6].x, cur[7].x);
        ((uint4*)(rowp + 8))[0] = make_uint4(cur[0].y, cur[1].y, cur[2].y, cur[3].y);
        ((uint4*)(rowp + 8))[1] = make_uint4(cur[4].y, cur[5].y, cur[6].y, cur[7].y);
#pragma unroll
        for (int s = 0; s < 4; ++s) {
            const uint* pr = aslab + (s * 16 + m_idx) * 20 + 2 * q_idx;
            BU ao, am;
            ao.u = *(const uint2*)pr;
            am.u = *(const uint2*)(pr + 8);
            accO0[s] = __builtin_amdgcn_mfma_f32_16x16x16f16(ao.h, bO[kk * 2 + 0], accO0[s], 0, 0, 0);
            accO1[s] = __builtin_amdgcn_mfma_f32_16x16x16f16(ao.h, bO[kk * 2 + 1], accO1[s], 0, 0, 0);
            accM[s]  = __builtin_amdgcn_mfma_f32_16x16x16f16(am.h, bM[kk], accM[s], 0, 0, 0);
        }
#pragma unroll
        for (int j = 0; j < 8; ++j) cur[j] = nxt[j];
    }

    // ---- write xs window from staged registers (latency already absorbed) ----
#pragma unroll
    for (int it = 0; it < 2; ++it)
        if (sidx[it] >= 0) {
            sm.s.xsA[sidx[it]] = sA[it];
            sm.s.xsB[sidx[it]] = sB[it];
        }

    const float* dc = dconst + b * 108;

    // ---- off D-exchange ----
#pragma unroll
    for (int s = 0; s < 4; ++s)
#pragma unroll
        for (int j = 0; j < 4; ++j) {
            int px = s * 16 + 4 * q_idx + j;
            union { __half2 h2; uint u; } pk;
            pk.h2 = __halves2half2(__float2half(accO0[s][j]),
                                   __float2half(accO1[s][j]));
            aslab[px * 20 + m_idx] = pk.u;
        }
    float facc[18];
    {
        const uint4* dr = (const uint4*)(aslab + lane * 20);
        uint4 d0 = dr[0], d1 = dr[1], d2 = dr[2], d3 = dr[3];
        uint du[16] = {d0.x, d0.y, d0.z, d0.w, d1.x, d1.y, d1.z, d1.w,
                       d2.x, d2.y, d2.z, d2.w, d3.x, d3.y, d3.z, d3.w};
        union { uint u; __half2 h2; } cv;
#pragma unroll
        for (int i = 0; i < 16; ++i) {
            cv.u = du[i];
            float2 f = __half22float2(cv.h2);
            facc[i] = f.x + dc[g * 18 + i];
            if (i < 2) facc[16 + i] = f.y + dc[g * 18 + 16 + i];
        }
    }

    // ---- mask D-exchange + softmax ----
    float macc[9];
    {
        float* fsl = (float*)aslab;
#pragma unroll
        for (int s = 0; s < 4; ++s)
#pragma unroll
            for (int j = 0; j < 4; ++j) {
                int px = s * 16 + 4 * q_idx + j;
                fsl[px * 20 + m_idx] = accM[s][j];
            }
#pragma unroll
        for (int k = 0; k < 9; ++k) macc[k] = fsl[lane * 20 + k] + dc[72 + g * 9 + k];
        float mx = macc[0];
#pragma unroll
        for (int k = 1; k < 9; ++k) mx = fmaxf(mx, macc[k]);
        float ssum = 0.f;
#pragma unroll
        for (int k = 0; k < 9; ++k) {
            float e = __expf(macc[k] - mx);
            macc[k] = e;
            ssum += e;
        }
        float inv = 1.f / ssum;
#pragma unroll
        for (int k = 0; k < 9; ++k) macc[k] *= inv;
    }

    // ---- gather-conv B-fragments (loaded late to cap register pressure) ----
    const uint2* wbp = wb + (size_t)(g * 9) * 64 + lane;
    f16x4 bfr[9];
#pragma unroll
    for (int k = 0; k < 9; ++k) { BU t; t.u = wbp[k * 64]; bfr[k] = t.h; }

    __syncthreads();    // xs staging visible to all; slab GEMM data consumed

    uint4* shvw = (uint4*)aslab + lane * 3;
    const _Float16* shvh = (const _Float16*)aslab;

    f32x4 acc[4];
#pragma unroll
    for (int s = 0; s < 4; ++s) acc[s] = (f32x4){0.f, 0.f, 0.f, 0.f};

#pragma unroll
    for (int k = 0; k < 9; ++k) {
        float mk = macc[k];
        float py = (float)(row + k / 3 - 1) + facc[k * 2 + 0];
        float px = (float)(col + k % 3 - 1) + facc[k * 2 + 1];
        float y0f = floorf(py), x0f = floorf(px);
        float wy = py - y0f, wx = px - x0f;
        int iy0 = (int)y0f, ix0 = (int)x0f;
        int iy1 = iy0 + 1, ix1 = ix0 + 1;
        float fy0 = (iy0 >= 0 && iy0 < IMG_H) ? (1.f - wy) : 0.f;
        float fy1 = (iy1 >= 0 && iy1 < IMG_H) ? wy : 0.f;
        float fx0 = (ix0 >= 0 && ix0 < IMG_W) ? (1.f - wx) : 0.f;
        float fx1 = (ix1 >= 0 && ix1 < IMG_W) ? wx : 0.f;
        __half2 f00h = __float2half2_rn(fy0 * fx0 * mk);
        __half2 f01h = __float2half2_rn(fy0 * fx1 * mk);
        __half2 f10h = __float2half2_rn(fy1 * fx0 * mk);
        __half2 f11h = __float2half2_rn(fy1 * fx1 * mk);
        int ly0 = iy0 - wr0; ly0 = ly0 < 0 ? 0 : (ly0 > 21 ? 21 : ly0);
        int ly1 = iy1 - wr0; ly1 = ly1 < 0 ? 0 : (ly1 > 21 ? 21 : ly1);
        int lx0 = ix0 - wc0; lx0 = lx0 < 0 ? 0 : (lx0 > 21 ? 21 : lx0);
        int lx1 = ix1 - wc0; lx1 = lx1 < 0 ? 0 : (lx1 > 21 ? 21 : lx1);
        int i00 = ly0 * 23 + lx0, i01 = ly0 * 23 + lx1;
        int i10 = ly1 * 23 + lx0, i11 = ly1 * 23 + lx1;
        union Q8 { uint4 u[2]; __half2 h2[8]; };
        Q8 q00, q01, q10, q11;
        q00.u[0] = sm.s.xsA[i00]; q00.u[1] = sm.s.xsB[i00];
        q01.u[0] = sm.s.xsA[i01]; q01.u[1] = sm.s.xsB[i01];
        q10.u[0] = sm.s.xsA[i10]; q10.u[1] = sm.s.xsB[i10];
        q11.u[0] = sm.s.xsA[i11]; q11.u[1] = sm.s.xsB[i11];
        union V8 { __half2 h2[4]; uint4 u; };
        V8 pa, pb;
#pragma unroll
        for (int i = 0; i < 4; ++i) {
            __half2 vh = __hmul2(f00h, q00.h2[i]);
            vh = __hfma2(f01h, q01.h2[i], vh);
            vh = __hfma2(f10h, q10.h2[i], vh);
            vh = __hfma2(f11h, q11.h2[i], vh);
            pa.h2[i] = vh;
        }
#pragma unroll
        for (int i = 4; i < 8; ++i) {
            __half2 vh = __hmul2(f00h, q00.h2[i]);
            vh = __hfma2(f01h, q01.h2[i], vh);
            vh = __hfma2(f10h, q10.h2[i], vh);
            vh = __hfma2(f11h, q11.h2[i], vh);
            pb.h2[i - 4] = vh;
        }
        shvw[0] = pa.u;
        shvw[1] = pb.u;
#pragma unroll
        for (int s = 0; s < 4; ++s) {
            f16x4 af = *(const f16x4*)(shvh +
                        ((size_t)(s * 16 + m_idx)) * 24 + q_idx * 4);
            acc[s] = __builtin_amdgcn_mfma_f32_16x16x16f16(af, bfr[k], acc[s], 0, 0, 0);
        }
    }

    __syncthreads();   // all waves done with xs window before aliasing shout

#pragma unroll
    for (int s = 0; s < 4; ++s)
#pragma unroll
        for (int j = 0; j < 4; ++j)
            sm.shout[(wv * 64 + s * 16 + 4 * q_idx + j) * 19 + m_idx] = acc[s][j];

    float* outp = out + ((size_t)b * 64 + g * 16) * HW + p;
#pragma unroll
    for (int o = 0; o < 16; ++o)
        outp[(size_t)o * HW] = sm.shout[tid * 19 + o] + bias[g * 16 + o];
}

// ---------------------------------------------------------------------------
extern "C" void kernel_launch(void* const* d_in, const int* in_sizes, int n_in,
                              void* d_out, int out_size, void* d_ws, size_t ws_size,
                              hipStream_t stream) {
    const float* x        = (const float*)d_in[0];
    const float* w_dw_off = (const float*)d_in[1];
    const float* b_dw_off = (const float*)d_in[2];
    const float* gn_off_g = (const float*)d_in[3];
    const float* gn_off_b = (const float*)d_in[4];
    const float* w_pw_off = (const float*)d_in[5];
    const float* b_pw_off = (const float*)d_in[6];
    const float* w_dw_m   = (const float*)d_in[7];
    const float* b_dw_m   = (const float*)d_in[8];
    const float* gn_m_g   = (const float*)d_in[9];
    const float* gn_m_b   = (const float*)d_in[10];
    const float* w_pw_m   = (const float*)d_in[11];
    const float* b_pw_m   = (const float*)d_in[12];
    const float* weight   = (const float*)d_in[13];
    const float* bias     = (const float*)d_in[14];

    float* ws = (float*)d_ws;
    uint2* t2p    = (uint2*)(ws + OFF_T2);
    __half* xT    = (__half*)(ws + OFF_XT);
    float* wT     = ws + OFF_WT;
    float* part   = ws + OFF_PART;
    const uint2* wb = (const uint2*)(ws + OFF_WB);
    const uint* wdw2 = (const uint*)(ws + OFF_WDW2);
    uint2* wbo    = (uint2*)(ws + OFF_WBO);
    uint2* wbm    = (uint2*)(ws + OFF_WBM);
    float* dconst = ws + OFF_DC;

    k_prep<<<50, 256, 0, stream>>>(w_pw_off, w_pw_m, weight, w_dw_off, w_dw_m, ws);
    k_trans<<<2048, 256, 0, stream>>>(x, xT);
    k_dw<<<4096, 256, 0, stream>>>(x, b_dw_off, b_dw_m, wdw2, t2p, part);
    k_finfold<<<8, 256, 0, stream>>>(part, gn_off_g, gn_off_b, gn_m_g, gn_m_b,
                                     wT, b_pw_off, b_pw_m, wbo, wbm, dconst);
    k_gthf<<<2048, 256, 0, stream>>>(t2p, wbo, wbm, dconst, xT, wb, bias, (float*)d_out);
}

// Round 19
// 102.251 us; speedup vs baseline: 1.0143x; 1.0143x over previous
//
#include <hip/hip_runtime.h>
#include <hip/hip_fp16.h>
#include <math.h>

#define HW     16384
#define IMG_H  128
#define IMG_W  128

typedef _Float16 f16x2 __attribute__((ext_vector_type(2)));
typedef __fp16 fp16v2 __attribute__((ext_vector_type(2)));
typedef _Float16 f16x4 __attribute__((ext_vector_type(4)));
typedef float f32x4 __attribute__((ext_vector_type(4)));

// ws layout in float units
#define OFF_T2    ((size_t)0)          // uint2[8*32*16384] (off-pair, m-pair) 33.5MB
#define OFF_XT    ((size_t)8388608)    // __half[32*16384*16] channel-last x, 16.8MB
#define OFF_WT    ((size_t)12582912)   // float[6912]  pw weights c-major
#define OFF_PART  ((size_t)12599040)   // float[16384] per-block GN partials
#define OFF_WB    ((size_t)19711744)   // uint2[4*9*64] f16 B-fragments (gather MFMA)
#define OFF_WDW2  ((size_t)19716352)   // uint[64*2*7*4] packed half2 dw weights
#define OFF_WBO   ((size_t)19719936)   // uint2[8*4*8*64]  pw-GEMM off B-frags
#define OFF_WBM   ((size_t)19752704)   // uint2[8*4*4*64]  pw-GEMM mask B-frags
#define OFF_DC    ((size_t)19769088)   // float[8*108]  GN-folded pw bias
// end = 19769952 floats = 79.1 MB

// ---------------------------------------------------------------------------
// k_prep: wT[c][108] (pw weights c-major), wb (gather MFMA B-frags),
// wdw2: packed half2 dw-weight pairs.
__global__ void k_prep(const float* __restrict__ wpw_off,
                       const float* __restrict__ wpw_m,
                       const float* __restrict__ wdef,
                       const float* __restrict__ wdwo,
                       const float* __restrict__ wdwm,
                       float* __restrict__ ws) {
    int i = blockIdx.x * 256 + threadIdx.x;
    if (i < 6912) {
        int c = i / 108, o = i % 108;
        ws[OFF_WT + i] = (o < 72) ? wpw_off[o * 64 + c] : wpw_m[(o - 72) * 64 + c];
    } else if (i < 9216) {
        int j = i - 6912;               // (g*9+tap)*64 + lane
        int lane = j & 63;
        int gt = j >> 6;
        int tap = gt % 9, g = gt / 9;
        int oc = lane & 15, qh = lane >> 4;
        union { ushort h[4]; uint2 u; } pk;
#pragma unroll
        for (int jj = 0; jj < 4; ++jj) {
            float wv = wdef[((g * 16 + oc) * 16 + (4 * qh + jj)) * 9 + tap];
            pk.h[jj] = __half_as_ushort(__float2half(wv));
        }
        ((uint2*)(ws + OFF_WB))[j] = pk.u;
    } else if (i < 12800) {
        int j = i - 9216;               // ((c*2+conv)*7+dy)*4 + q
        int q = j & 3;
        int r = j >> 2;
        int dy = r % 7;
        int cv = (r / 7) & 1;
        int c = r / 14;
        const float* src = cv ? wdwm : wdwo;
        int dx0 = q * 2;
        float w0 = src[c * 49 + dy * 7 + dx0];
        float w1 = (dx0 + 1 < 7) ? src[c * 49 + dy * 7 + dx0 + 1] : 0.f;
        union { __half h[2]; uint u; } pk;
        pk.h[0] = __float2half(w0);
        pk.h[1] = __float2half(w1);
        ((uint*)(ws + OFF_WDW2))[j] = pk.u;
    }
}

// ---------------------------------------------------------------------------
// k_dw: both depthwise 7x7 convs via v_dot2_f32_f16; 2 channels per thread;
// writes channel-PAIRED layout t2p[b][c2][p]. FUSED k_trans: the dy==3 row
// IS x[c][row][*] — capture it and emit xT[bg][p][16] fp16 channel-pairs.
__global__ __launch_bounds__(256) void k_dw(const float* __restrict__ x,
                                            const float* __restrict__ bdwo,
                                            const float* __restrict__ bdwm,
                                            const uint* __restrict__ wdw2,
                                            uint2* __restrict__ t2p,
                                            __half* __restrict__ xT,
                                            float* __restrict__ partial) {
    int bid = blockIdx.x;
    int b = bid >> 9;                       // 32 c2 x 16 stripes per b
    int c2 = (bid >> 4) & 31;
    int stripe = (bid & 15) * 8;
    int t = threadIdx.x;
    int cb = t & 31;                        // 4-col block
    int row = stripe + (t >> 5);
    int c0 = c2 * 2;

    float vo[2][4], vm[2][4];
    float4 cen[2];
    float s1o = 0.f, s2o = 0.f, s1m = 0.f, s2m = 0.f;
    union CV { fp16v2 v; f16x2 h; };
    union WU { uint u; f16x2 h; };

#pragma unroll
    for (int ch = 0; ch < 2; ++ch) {
        int c = c0 + ch;
        const float4* pl = (const float4*)(x + ((size_t)(b * 64 + c)) * HW);
        const uint* wp = wdw2 + c * 56;
        float acco[4] = {0.f, 0.f, 0.f, 0.f};
        float accm[4] = {0.f, 0.f, 0.f, 0.f};
#pragma unroll
        for (int dy = 0; dy < 7; ++dy) {
            int iy = row - 3 + dy;
            if (iy >= 0 && iy < IMG_H) {
                const float4* prow = pl + iy * 32;
                float4 f4 = prow[cb];
                float4 f4m = prow[cb == 0 ? 0 : cb - 1];
                float4 f4p = prow[cb == 31 ? 31 : cb + 1];
                if (dy == 3) cen[ch] = f4;
                bool le = (cb == 0), re = (cb == 31);
                float v[11];
                v[0] = le ? 0.f : f4m.y;
                v[1] = le ? 0.f : f4m.z;
                v[2] = le ? 0.f : f4m.w;
                v[3] = f4.x; v[4] = f4.y; v[5] = f4.z; v[6] = f4.w;
                v[7] = re ? 0.f : f4p.x;
                v[8] = re ? 0.f : f4p.y;
                v[9] = re ? 0.f : f4p.z;
                v[10] = re ? 0.f : f4p.w;
                f16x2 hp[10];
#pragma unroll
                for (int d = 0; d < 10; ++d) {
                    CV cv;
                    cv.v = __builtin_amdgcn_cvt_pkrtz(v[d], v[d + 1]);
                    hp[d] = cv.h;
                }
#pragma unroll
                for (int cc = 0; cc < 4; ++cc) {
                    WU w0, w1, w2, w3, u0, u1, u2, u3;
                    w0.u = wp[dy * 4 + 0]; w1.u = wp[dy * 4 + 1];
                    w2.u = wp[dy * 4 + 2]; w3.u = wp[dy * 4 + 3];
                    u0.u = wp[28 + dy * 4 + 0]; u1.u = wp[28 + dy * 4 + 1];
                    u2.u = wp[28 + dy * 4 + 2]; u3.u = wp[28 + dy * 4 + 3];
                    float ao = acco[cc], am = accm[cc];
                    ao = __builtin_amdgcn_fdot2(hp[cc],     w0.h, ao, false);
                    ao = __builtin_amdgcn_fdot2(hp[cc + 2], w1.h, ao, false);
                    ao = __builtin_amdgcn_fdot2(hp[cc + 4], w2.h, ao, false);
                    ao = __builtin_amdgcn_fdot2(hp[cc + 6], w3.h, ao, false);
                    am = __builtin_amdgcn_fdot2(hp[cc],     u0.h, am, false);
                    am = __builtin_amdgcn_fdot2(hp[cc + 2], u1.h, am, false);
                    am = __builtin_amdgcn_fdot2(hp[cc + 4], u2.h, am, false);
                    am = __builtin_amdgcn_fdot2(hp[cc + 6], u3.h, am, false);
                    acco[cc] = ao; accm[cc] = am;
                }
            }
        }
        float bo = bdwo[c], bm = bdwm[c];
#pragma unroll
        for (int cc = 0; cc < 4; ++cc) {
            float o_ = acco[cc] + bo, m_ = accm[cc] + bm;
            vo[ch][cc] = o_; vm[ch][cc] = m_;
            s1o += o_; s2o += o_ * o_; s1m += m_; s2m += m_ * m_;
        }
    }

    union { uint2 u2[4]; uint4 u4[2]; } ot;
#pragma unroll
    for (int cc = 0; cc < 4; ++cc) {
        ot.u2[cc].x = (uint)__half_as_ushort(__float2half(vo[0][cc])) |
                      ((uint)__half_as_ushort(__float2half(vo[1][cc])) << 16);
        ot.u2[cc].y = (uint)__half_as_ushort(__float2half(vm[0][cc])) |
                      ((uint)__half_as_ushort(__float2half(vm[1][cc])) << 16);
    }
    uint4* dst = (uint4*)(t2p + ((size_t)(b * 32 + c2) * HW + row * IMG_W + cb * 4));
    dst[0] = ot.u4[0];
    dst[1] = ot.u4[1];

    // ---- fused k_trans: write raw center row as fp16 channel-pairs ----
    {
        int bg = b * 4 + (c0 >> 4);
        int cw = c0 & 15;
        uint* xtw = (uint*)(xT + ((size_t)bg * HW + row * IMG_W + cb * 4) * 16 + cw);
        float ca[4] = {cen[0].x, cen[0].y, cen[0].z, cen[0].w};
        float cbv[4] = {cen[1].x, cen[1].y, cen[1].z, cen[1].w};
#pragma unroll
        for (int j = 0; j < 4; ++j) {
            xtw[j * 8] = (uint)__half_as_ushort(__float2half(ca[j])) |
                         ((uint)__half_as_ushort(__float2half(cbv[j])) << 16);
        }
    }

#pragma unroll
    for (int d = 32; d; d >>= 1) {
        s1o += __shfl_down(s1o, d);
        s2o += __shfl_down(s2o, d);
        s1m += __shfl_down(s1m, d);
        s2m += __shfl_down(s2m, d);
    }
    __shared__ float red[4][4];
    if ((t & 63) == 0) {
        int w = t >> 6;
        red[w][0] = s1o; red[w][1] = s2o; red[w][2] = s1m; red[w][3] = s2m;
    }
    __syncthreads();
    if (t < 4) {
        float v = red[0][t] + red[1][t] + red[2][t] + red[3][t];
        partial[(size_t)bid * 4 + t] = v;
    }
}

// ---------------------------------------------------------------------------
// k_finfold: one block per sample. Phase 1: reduce partials -> GN affine in
// LDS. Phase 2: emit GN-folded pw-GEMM MFMA B-fragments + dconst.
__global__ __launch_bounds__(256) void k_finfold(const float* __restrict__ partial,
                      const float* __restrict__ gog, const float* __restrict__ gob,
                      const float* __restrict__ gmg, const float* __restrict__ gmb,
                      const float* __restrict__ wT,
                      const float* __restrict__ bpo,
                      const float* __restrict__ bpm,
                      uint2* __restrict__ wbo,
                      uint2* __restrict__ wbm,
                      float* __restrict__ dconst) {
    __shared__ float adsh[256];
    int b = blockIdx.x, t = threadIdx.x;
    {
        const float4* pp = (const float4*)partial + (size_t)b * 512;
        float4 s = make_float4(0.f, 0.f, 0.f, 0.f);
#pragma unroll
        for (int i = 0; i < 2; ++i) {
            float4 v = pp[t + i * 256];
            s.x += v.x; s.y += v.y; s.z += v.z; s.w += v.w;
        }
#pragma unroll
        for (int d = 32; d; d >>= 1) {
            s.x += __shfl_down(s.x, d);
            s.y += __shfl_down(s.y, d);
            s.z += __shfl_down(s.z, d);
            s.w += __shfl_down(s.w, d);
        }
        __shared__ float red[4][4];
        if ((t & 63) == 0) {
            int w = t >> 6;
            red[w][0] = s.x; red[w][1] = s.y; red[w][2] = s.z; red[w][3] = s.w;
        }
        __syncthreads();
        if (t < 64) {
            float s1o = red[0][0] + red[1][0] + red[2][0] + red[3][0];
            float s2o = red[0][1] + red[1][1] + red[2][1] + red[3][1];
            float s1m = red[0][2] + red[1][2] + red[2][2] + red[3][2];
            float s2m = red[0][3] + red[1][3] + red[2][3] + red[3][3];
            int c = t;
            const float invN = 1.f / 1048576.f;
            float m_o = s1o * invN;
            float v_o = s2o * invN - m_o * m_o;
            float i_o = rsqrtf(v_o + 1e-5f);
            float m_m = s1m * invN;
            float v_m = s2m * invN - m_m * m_m;
            float i_m = rsqrtf(v_m + 1e-5f);
            adsh[c * 4 + 0] = i_o * gog[c];
            adsh[c * 4 + 1] = gob[c] - m_o * (i_o * gog[c]);
            adsh[c * 4 + 2] = i_m * gmg[c];
            adsh[c * 4 + 3] = gmb[c] - m_m * (i_m * gmg[c]);
        }
        __syncthreads();
    }
    for (int i = t; i < 2048; i += 256) {       // off frags
        int lane = i & 63;
        int f = i >> 6;
        int g = f >> 3, kk = (f >> 1) & 3, nf = f & 1;
        int n = lane & 15, q = lane >> 4;
        int out = nf * 16 + n;
        union { ushort h[4]; uint2 u; } pk;
#pragma unroll
        for (int jj = 0; jj < 4; ++jj) {
            int ch = kk * 16 + 4 * q + jj;
            float w = (out < 18) ? adsh[ch * 4 + 0] * wT[ch * 108 + g * 18 + out] : 0.f;
            pk.h[jj] = __half_as_ushort(__float2half(w));
        }
        wbo[((size_t)(b * 4) + g) * 8 * 64 + (size_t)(kk * 2 + nf) * 64 + lane] = pk.u;
    }
    for (int i = t; i < 1024; i += 256) {       // mask frags
        int lane = i & 63;
        int f = i >> 6;
        int g = f >> 2, kk = f & 3;
        int n = lane & 15, q = lane >> 4;
        union { ushort h[4]; uint2 u; } pk;
#pragma unroll
        for (int jj = 0; jj < 4; ++jj) {
            int ch = kk * 16 + 4 * q + jj;
            float w = (n < 9) ? adsh[ch * 4 + 2] * wT[ch * 108 + 72 + g * 9 + n] : 0.f;
            pk.h[jj] = __half_as_ushort(__float2half(w));
        }
        wbm[((size_t)(b * 4) + g) * 4 * 64 + (size_t)kk * 64 + lane] = pk.u;
    }
    if (t < 108) {
        float s = (t < 72) ? bpo[t] : bpm[t - 72];
        for (int c = 0; c < 64; ++c) {
            float d = (t < 72) ? adsh[c * 4 + 1] : adsh[c * 4 + 3];
            s = fmaf(d, wT[c * 108 + t], s);
        }
        dconst[b * 108 + t] = s;
    }
}

// ---------------------------------------------------------------------------
// k_gthf: FUSED MFMA pw-GEMM + softmax + LDS-staged bilinear gather + MFMA.
// EXACT R17 body (proven 49.6us, 64 VGPR, no spills). Do not re-pipeline:
// R14/R15/R18 all regressed from register-budget perturbation.
__global__ __launch_bounds__(256, 4) void k_gthf(const uint2* __restrict__ t2p,
                                                 const uint2* __restrict__ wbo,
                                                 const uint2* __restrict__ wbm,
                                                 const float* __restrict__ dconst,
                                                 const __half* __restrict__ xT,
                                                 const uint2* __restrict__ wb,
                                                 const float* __restrict__ bias,
                                                 float* __restrict__ out) {
    __shared__ union SMem {
        struct {
            uint4 xsA[506];     // 22 rows x stride 23, ch 0-7
            uint4 xsB[506];     // ch 8-15
            uint  slab[5120];   // 4 waves x [64 px][20 uint] (A/D/shv alias)
        } s;
        float shout[4864];      // 256 px x stride 19 (aliased, post-barrier)
    } sm;

    int tid = threadIdx.x;
    int bid = blockIdx.x;
    int bg = bid >> 6;                      // slice-major: g-variants same XCD
    int tile = bid & 63;
    int tr = tile >> 3, tc = tile & 7;
    int r0 = tr * 16, c0 = tc * 16;
    int g = bg & 3, b = bg >> 2;
    int wr0 = r0 - 3, wc0 = c0 - 3;

    const __half* xg = xT + (size_t)bg * HW * 16;

#pragma unroll
    for (int it = 0; it < 2; ++it) {
        int idx = tid + it * 256;
        if (idx < 484) {
            int ly = idx / 22, lx = idx - ly * 22;
            int sr = wr0 + ly; sr = sr < 0 ? 0 : (sr > 127 ? 127 : sr);
            int sc = wc0 + lx; sc = sc < 0 ? 0 : (sc > 127 ? 127 : sc);
            const uint4* src = (const uint4*)(xg + (size_t)(sr * IMG_W + sc) * 16);
            sm.s.xsA[ly * 23 + lx] = src[0];
            sm.s.xsB[ly * 23 + lx] = src[1];
        }
    }

    int row = r0 + (tid >> 4), col = c0 + (tid & 15);
    int p = row * IMG_W + col;
    int lane = tid & 63, wv = tid >> 6;
    int m_idx = lane & 15, q_idx = lane >> 4;

    union BU { uint2 u; f16x4 h; };

    const uint2* wboP = wbo + ((size_t)(b * 4) + g) * 8 * 64 + lane;
    const uint2* wbmP = wbm + ((size_t)(b * 4) + g) * 4 * 64 + lane;
    f16x4 bO[8], bM[4];
#pragma unroll
    for (int i = 0; i < 8; ++i) { BU t; t.u = wboP[i * 64]; bO[i] = t.h; }
#pragma unroll
    for (int i = 0; i < 4; ++i) { BU t; t.u = wbmP[i * 64]; bM[i] = t.h; }

    const uint2* wbp = wb + (size_t)(g * 9) * 64 + lane;
    f16x4 bfr[9];
#pragma unroll
    for (int k = 0; k < 9; ++k) { BU t; t.u = wbp[k * 64]; bfr[k] = t.h; }

    uint* aslab = sm.s.slab + wv * 1280;        // [64 px][20 uint]
    const uint2* tp = t2p + (size_t)b * 32 * HW + p;

    f32x4 accO0[4], accO1[4], accM[4];
#pragma unroll
    for (int s = 0; s < 4; ++s) {
        accO0[s] = (f32x4){0.f, 0.f, 0.f, 0.f};
        accO1[s] = (f32x4){0.f, 0.f, 0.f, 0.f};
        accM[s]  = (f32x4){0.f, 0.f, 0.f, 0.f};
    }

#pragma unroll
    for (int kk = 0; kk < 4; ++kk) {
        uint2 v[8];
#pragma unroll
        for (int j = 0; j < 8; ++j) v[j] = tp[(size_t)(kk * 8 + j) * HW];
        uint* rowp = aslab + lane * 20;
        ((uint4*)rowp)[0] = make_uint4(v[0].x, v[1].x, v[2].x, v[3].x);
        ((uint4*)rowp)[1] = make_uint4(v[4].x, v[5].x, v[6].x, v[7].x);
        ((uint4*)(rowp + 8))[0] = make_uint4(v[0].y, v[1].y, v[2].y, v[3].y);
        ((uint4*)(rowp + 8))[1] = make_uint4(v[4].y, v[5].y, v[6].y, v[7].y);
#pragma unroll
        for (int s = 0; s < 4; ++s) {
            const uint* pr = aslab + (s * 16 + m_idx) * 20 + 2 * q_idx;
            BU ao, am;
            ao.u = *(const uint2*)pr;
            am.u = *(const uint2*)(pr + 8);
            accO0[s] = __builtin_amdgcn_mfma_f32_16x16x16f16(ao.h, bO[kk * 2 + 0], accO0[s], 0, 0, 0);
            accO1[s] = __builtin_amdgcn_mfma_f32_16x16x16f16(ao.h, bO[kk * 2 + 1], accO1[s], 0, 0, 0);
            accM[s]  = __builtin_amdgcn_mfma_f32_16x16x16f16(am.h, bM[kk], accM[s], 0, 0, 0);
        }
    }

    const float* dc = dconst + b * 108;

#pragma unroll
    for (int s = 0; s < 4; ++s)
#pragma unroll
        for (int j = 0; j < 4; ++j) {
            int px = s * 16 + 4 * q_idx + j;
            union { __half2 h2; uint u; } pk;
            pk.h2 = __halves2half2(__float2half(accO0[s][j]),
                                   __float2half(accO1[s][j]));
            aslab[px * 20 + m_idx] = pk.u;
        }
    float facc[18];
    {
        const uint4* dr = (const uint4*)(aslab + lane * 20);
        uint4 d0 = dr[0], d1 = dr[1], d2 = dr[2], d3 = dr[3];
        uint du[16] = {d0.x, d0.y, d0.z, d0.w, d1.x, d1.y, d1.z, d1.w,
                       d2.x, d2.y, d2.z, d2.w, d3.x, d3.y, d3.z, d3.w};
        union { uint u; __half2 h2; } cv;
#pragma unroll
        for (int i = 0; i < 16; ++i) {
            cv.u = du[i];
            float2 f = __half22float2(cv.h2);
            facc[i] = f.x + dc[g * 18 + i];
            if (i < 2) facc[16 + i] = f.y + dc[g * 18 + 16 + i];
        }
    }

    {
        float* fsl = (float*)aslab;
#pragma unroll
        for (int s = 0; s < 4; ++s)
#pragma unroll
            for (int j = 0; j < 4; ++j) {
                int px = s * 16 + 4 * q_idx + j;
                fsl[px * 20 + m_idx] = accM[s][j];
            }
        float macc[9];
#pragma unroll
        for (int k = 0; k < 9; ++k) macc[k] = fsl[lane * 20 + k] + dc[72 + g * 9 + k];
        float mx = macc[0];
#pragma unroll
        for (int k = 1; k < 9; ++k) mx = fmaxf(mx, macc[k]);
        float ssum = 0.f;
#pragma unroll
        for (int k = 0; k < 9; ++k) {
            float e = __expf(macc[k] - mx);
            macc[k] = e;
            ssum += e;
        }
        float inv = 1.f / ssum;
#pragma unroll
        for (int k = 0; k < 9; ++k) macc[k] *= inv;

        __syncthreads();    // staging visible to all; slab GEMM data consumed

        uint4* shvw = (uint4*)aslab + lane * 3;
        const _Float16* shvh = (const _Float16*)aslab;

        f32x4 acc[4];
#pragma unroll
        for (int s = 0; s < 4; ++s) acc[s] = (f32x4){0.f, 0.f, 0.f, 0.f};

#pragma unroll
        for (int k = 0; k < 9; ++k) {
            float mk = macc[k];
            float py = (float)(row + k / 3 - 1) + facc[k * 2 + 0];
            float px = (float)(col + k % 3 - 1) + facc[k * 2 + 1];
            float y0f = floorf(py), x0f = floorf(px);
            float wy = py - y0f, wx = px - x0f;
            int iy0 = (int)y0f, ix0 = (int)x0f;
            int iy1 = iy0 + 1, ix1 = ix0 + 1;
            float fy0 = (iy0 >= 0 && iy0 < IMG_H) ? (1.f - wy) : 0.f;
            float fy1 = (iy1 >= 0 && iy1 < IMG_H) ? wy : 0.f;
            float fx0 = (ix0 >= 0 && ix0 < IMG_W) ? (1.f - wx) : 0.f;
            float fx1 = (ix1 >= 0 && ix1 < IMG_W) ? wx : 0.f;
            __half2 f00h = __float2half2_rn(fy0 * fx0 * mk);
            __half2 f01h = __float2half2_rn(fy0 * fx1 * mk);
            __half2 f10h = __float2half2_rn(fy1 * fx0 * mk);
            __half2 f11h = __float2half2_rn(fy1 * fx1 * mk);
            int ly0 = iy0 - wr0; ly0 = ly0 < 0 ? 0 : (ly0 > 21 ? 21 : ly0);
            int ly1 = iy1 - wr0; ly1 = ly1 < 0 ? 0 : (ly1 > 21 ? 21 : ly1);
            int lx0 = ix0 - wc0; lx0 = lx0 < 0 ? 0 : (lx0 > 21 ? 21 : lx0);
            int lx1 = ix1 - wc0; lx1 = lx1 < 0 ? 0 : (lx1 > 21 ? 21 : lx1);
            int i00 = ly0 * 23 + lx0, i01 = ly0 * 23 + lx1;
            int i10 = ly1 * 23 + lx0, i11 = ly1 * 23 + lx1;
            union Q8 { uint4 u[2]; __half2 h2[8]; };
            Q8 q00, q01, q10, q11;
            q00.u[0] = sm.s.xsA[i00]; q00.u[1] = sm.s.xsB[i00];
            q01.u[0] = sm.s.xsA[i01]; q01.u[1] = sm.s.xsB[i01];
            q10.u[0] = sm.s.xsA[i10]; q10.u[1] = sm.s.xsB[i10];
            q11.u[0] = sm.s.xsA[i11]; q11.u[1] = sm.s.xsB[i11];
            union V8 { __half2 h2[4]; uint4 u; };
            V8 pa, pb;
#pragma unroll
            for (int i = 0; i < 4; ++i) {
                __half2 vh = __hmul2(f00h, q00.h2[i]);
                vh = __hfma2(f01h, q01.h2[i], vh);
                vh = __hfma2(f10h, q10.h2[i], vh);
                vh = __hfma2(f11h, q11.h2[i], vh);
                pa.h2[i] = vh;
            }
#pragma unroll
            for (int i = 4; i < 8; ++i) {
                __half2 vh = __hmul2(f00h, q00.h2[i]);
                vh = __hfma2(f01h, q01.h2[i], vh);
                vh = __hfma2(f10h, q10.h2[i], vh);
                vh = __hfma2(f11h, q11.h2[i], vh);
                pb.h2[i - 4] = vh;
            }
            shvw[0] = pa.u;
            shvw[1] = pb.u;
#pragma unroll
            for (int s = 0; s < 4; ++s) {
                f16x4 af = *(const f16x4*)(shvh +
                            ((size_t)(s * 16 + m_idx)) * 24 + q_idx * 4);
                acc[s] = __builtin_amdgcn_mfma_f32_16x16x16f16(af, bfr[k], acc[s], 0, 0, 0);
            }
        }

        __syncthreads();   // all waves done with xs window before aliasing shout

#pragma unroll
        for (int s = 0; s < 4; ++s)
#pragma unroll
            for (int j = 0; j < 4; ++j)
                sm.shout[(wv * 64 + s * 16 + 4 * q_idx + j) * 19 + m_idx] = acc[s][j];

        float* outp = out + ((size_t)b * 64 + g * 16) * HW + p;
#pragma unroll
        for (int o = 0; o < 16; ++o)
            outp[(size_t)o * HW] = sm.shout[tid * 19 + o] + bias[g * 16 + o];
    }
}

// ---------------------------------------------------------------------------
extern "C" void kernel_launch(void* const* d_in, const int* in_sizes, int n_in,
                              void* d_out, int out_size, void* d_ws, size_t ws_size,
                              hipStream_t stream) {
    const float* x        = (const float*)d_in[0];
    const float* w_dw_off = (const float*)d_in[1];
    const float* b_dw_off = (const float*)d_in[2];
    const float* gn_off_g = (const float*)d_in[3];
    const float* gn_off_b = (const float*)d_in[4];
    const float* w_pw_off = (const float*)d_in[5];
    const float* b_pw_off = (const float*)d_in[6];
    const float* w_dw_m   = (const float*)d_in[7];
    const float* b_dw_m   = (const float*)d_in[8];
    const float* gn_m_g   = (const float*)d_in[9];
    const float* gn_m_b   = (const float*)d_in[10];
    const float* w_pw_m   = (const float*)d_in[11];
    const float* b_pw_m   = (const float*)d_in[12];
    const float* weight   = (const float*)d_in[13];
    const float* bias     = (const float*)d_in[14];

    float* ws = (float*)d_ws;
    uint2* t2p    = (uint2*)(ws + OFF_T2);
    __half* xT    = (__half*)(ws + OFF_XT);
    float* wT     = ws + OFF_WT;
    float* part   = ws + OFF_PART;
    const uint2* wb = (const uint2*)(ws + OFF_WB);
    const uint* wdw2 = (const uint*)(ws + OFF_WDW2);
    uint2* wbo    = (uint2*)(ws + OFF_WBO);
    uint2* wbm    = (uint2*)(ws + OFF_WBM);
    float* dconst = ws + OFF_DC;

    k_prep<<<50, 256, 0, stream>>>(w_pw_off, w_pw_m, weight, w_dw_off, w_dw_m, ws);
    k_dw<<<4096, 256, 0, stream>>>(x, b_dw_off, b_dw_m, wdw2, t2p, xT, part);
    k_finfold<<<8, 256, 0, stream>>>(part, gn_off_g, gn_off_b, gn_m_g, gn_m_b,
                                     wT, b_pw_off, b_pw_m, wbo, wbm, dconst);
    k_gthf<<<2048, 256, 0, stream>>>(t2p, wbo, wbm, dconst, xT, wb, bias, (float*)d_out);
}

// Round 20
// 92.636 us; speedup vs baseline: 1.1195x; 1.1038x over previous
//
#include <hip/hip_runtime.h>
#include <hip/hip_fp16.h>
#include <math.h>

#define HW     16384
#define IMG_H  128
#define IMG_W  128

typedef _Float16 f16x2 __attribute__((ext_vector_type(2)));
typedef __fp16 fp16v2 __attribute__((ext_vector_type(2)));
typedef _Float16 f16x4 __attribute__((ext_vector_type(4)));
typedef float f32x4 __attribute__((ext_vector_type(4)));

// ws layout in float units
#define OFF_T2    ((size_t)0)          // uint2[8*32*16384] (off-pair, m-pair) 33.5MB
#define OFF_XT    ((size_t)8388608)    // uint[32*8*16384] ch-pair planes, 16.8MB
#define OFF_WT    ((size_t)12582912)   // float[6912]  pw weights c-major
#define OFF_PART  ((size_t)12599040)   // float[16384] per-block GN partials
#define OFF_WB    ((size_t)19711744)   // uint2[4*9*64] f16 B-fragments (gather MFMA)
#define OFF_WDW2  ((size_t)19716352)   // uint[64*2*7*4] packed half2 dw weights
#define OFF_WBO   ((size_t)19719936)   // uint2[8*4*8*64]  pw-GEMM off B-frags
#define OFF_WBM   ((size_t)19752704)   // uint2[8*4*4*64]  pw-GEMM mask B-frags
#define OFF_DC    ((size_t)19769088)   // float[8*108]  GN-folded pw bias
// end = 19769952 floats = 79.1 MB

// ---------------------------------------------------------------------------
// k_prep: wT[c][108] (pw weights c-major), wb (gather MFMA B-frags),
// wdw2: packed half2 dw-weight pairs.
__global__ void k_prep(const float* __restrict__ wpw_off,
                       const float* __restrict__ wpw_m,
                       const float* __restrict__ wdef,
                       const float* __restrict__ wdwo,
                       const float* __restrict__ wdwm,
                       float* __restrict__ ws) {
    int i = blockIdx.x * 256 + threadIdx.x;
    if (i < 6912) {
        int c = i / 108, o = i % 108;
        ws[OFF_WT + i] = (o < 72) ? wpw_off[o * 64 + c] : wpw_m[(o - 72) * 64 + c];
    } else if (i < 9216) {
        int j = i - 6912;               // (g*9+tap)*64 + lane
        int lane = j & 63;
        int gt = j >> 6;
        int tap = gt % 9, g = gt / 9;
        int oc = lane & 15, qh = lane >> 4;
        union { ushort h[4]; uint2 u; } pk;
#pragma unroll
        for (int jj = 0; jj < 4; ++jj) {
            float wv = wdef[((g * 16 + oc) * 16 + (4 * qh + jj)) * 9 + tap];
            pk.h[jj] = __half_as_ushort(__float2half(wv));
        }
        ((uint2*)(ws + OFF_WB))[j] = pk.u;
    } else if (i < 12800) {
        int j = i - 9216;               // ((c*2+conv)*7+dy)*4 + q
        int q = j & 3;
        int r = j >> 2;
        int dy = r % 7;
        int cv = (r / 7) & 1;
        int c = r / 14;
        const float* src = cv ? wdwm : wdwo;
        int dx0 = q * 2;
        float w0 = src[c * 49 + dy * 7 + dx0];
        float w1 = (dx0 + 1 < 7) ? src[c * 49 + dy * 7 + dx0 + 1] : 0.f;
        union { __half h[2]; uint u; } pk;
        pk.h[0] = __float2half(w0);
        pk.h[1] = __float2half(w1);
        ((uint*)(ws + OFF_WDW2))[j] = pk.u;
    }
}

// ---------------------------------------------------------------------------
// k_dw: both depthwise 7x7 convs via v_dot2_f32_f16; 2 channels per thread;
// writes channel-PAIRED layout t2p[b][c2][p]. FUSED k_trans: the dy==3 row
// IS x[c][row][*]; emitted as ch-pair PLANES xTp[bg][pc][p] -> one coalesced
// uint4 store (R19's 32B-stride scatter was the regression; layout fixes it).
__global__ __launch_bounds__(256) void k_dw(const float* __restrict__ x,
                                            const float* __restrict__ bdwo,
                                            const float* __restrict__ bdwm,
                                            const uint* __restrict__ wdw2,
                                            uint2* __restrict__ t2p,
                                            uint* __restrict__ xTp,
                                            float* __restrict__ partial) {
    int bid = blockIdx.x;
    int b = bid >> 9;                       // 32 c2 x 16 stripes per b
    int c2 = (bid >> 4) & 31;
    int stripe = (bid & 15) * 8;
    int t = threadIdx.x;
    int cb = t & 31;                        // 4-col block
    int row = stripe + (t >> 5);
    int c0 = c2 * 2;

    float vo[2][4], vm[2][4];
    float4 cen[2];
    float s1o = 0.f, s2o = 0.f, s1m = 0.f, s2m = 0.f;
    union CV { fp16v2 v; f16x2 h; };
    union WU { uint u; f16x2 h; };

#pragma unroll
    for (int ch = 0; ch < 2; ++ch) {
        int c = c0 + ch;
        const float4* pl = (const float4*)(x + ((size_t)(b * 64 + c)) * HW);
        const uint* wp = wdw2 + c * 56;
        float acco[4] = {0.f, 0.f, 0.f, 0.f};
        float accm[4] = {0.f, 0.f, 0.f, 0.f};
#pragma unroll
        for (int dy = 0; dy < 7; ++dy) {
            int iy = row - 3 + dy;
            if (iy >= 0 && iy < IMG_H) {
                const float4* prow = pl + iy * 32;
                float4 f4 = prow[cb];
                float4 f4m = prow[cb == 0 ? 0 : cb - 1];
                float4 f4p = prow[cb == 31 ? 31 : cb + 1];
                if (dy == 3) cen[ch] = f4;
                bool le = (cb == 0), re = (cb == 31);
                float v[11];
                v[0] = le ? 0.f : f4m.y;
                v[1] = le ? 0.f : f4m.z;
                v[2] = le ? 0.f : f4m.w;
                v[3] = f4.x; v[4] = f4.y; v[5] = f4.z; v[6] = f4.w;
                v[7] = re ? 0.f : f4p.x;
                v[8] = re ? 0.f : f4p.y;
                v[9] = re ? 0.f : f4p.z;
                v[10] = re ? 0.f : f4p.w;
                f16x2 hp[10];
#pragma unroll
                for (int d = 0; d < 10; ++d) {
                    CV cv;
                    cv.v = __builtin_amdgcn_cvt_pkrtz(v[d], v[d + 1]);
                    hp[d] = cv.h;
                }
#pragma unroll
                for (int cc = 0; cc < 4; ++cc) {
                    WU w0, w1, w2, w3, u0, u1, u2, u3;
                    w0.u = wp[dy * 4 + 0]; w1.u = wp[dy * 4 + 1];
                    w2.u = wp[dy * 4 + 2]; w3.u = wp[dy * 4 + 3];
                    u0.u = wp[28 + dy * 4 + 0]; u1.u = wp[28 + dy * 4 + 1];
                    u2.u = wp[28 + dy * 4 + 2]; u3.u = wp[28 + dy * 4 + 3];
                    float ao = acco[cc], am = accm[cc];
                    ao = __builtin_amdgcn_fdot2(hp[cc],     w0.h, ao, false);
                    ao = __builtin_amdgcn_fdot2(hp[cc + 2], w1.h, ao, false);
                    ao = __builtin_amdgcn_fdot2(hp[cc + 4], w2.h, ao, false);
                    ao = __builtin_amdgcn_fdot2(hp[cc + 6], w3.h, ao, false);
                    am = __builtin_amdgcn_fdot2(hp[cc],     u0.h, am, false);
                    am = __builtin_amdgcn_fdot2(hp[cc + 2], u1.h, am, false);
                    am = __builtin_amdgcn_fdot2(hp[cc + 4], u2.h, am, false);
                    am = __builtin_amdgcn_fdot2(hp[cc + 6], u3.h, am, false);
                    acco[cc] = ao; accm[cc] = am;
                }
            }
        }
        float bo = bdwo[c], bm = bdwm[c];
#pragma unroll
        for (int cc = 0; cc < 4; ++cc) {
            float o_ = acco[cc] + bo, m_ = accm[cc] + bm;
            vo[ch][cc] = o_; vm[ch][cc] = m_;
            s1o += o_; s2o += o_ * o_; s1m += m_; s2m += m_ * m_;
        }
    }

    union { uint2 u2[4]; uint4 u4[2]; } ot;
#pragma unroll
    for (int cc = 0; cc < 4; ++cc) {
        ot.u2[cc].x = (uint)__half_as_ushort(__float2half(vo[0][cc])) |
                      ((uint)__half_as_ushort(__float2half(vo[1][cc])) << 16);
        ot.u2[cc].y = (uint)__half_as_ushort(__float2half(vm[0][cc])) |
                      ((uint)__half_as_ushort(__float2half(vm[1][cc])) << 16);
    }
    uint4* dst = (uint4*)(t2p + ((size_t)(b * 32 + c2) * HW + row * IMG_W + cb * 4));
    dst[0] = ot.u4[0];
    dst[1] = ot.u4[1];

    // ---- fused k_trans: coalesced uint4 store into ch-pair plane ----
    {
        int bg = b * 4 + (c0 >> 4);
        int pc = c2 & 7;
        uint4 pk4;
        pk4.x = (uint)__half_as_ushort(__float2half(cen[0].x)) |
                ((uint)__half_as_ushort(__float2half(cen[1].x)) << 16);
        pk4.y = (uint)__half_as_ushort(__float2half(cen[0].y)) |
                ((uint)__half_as_ushort(__float2half(cen[1].y)) << 16);
        pk4.z = (uint)__half_as_ushort(__float2half(cen[0].z)) |
                ((uint)__half_as_ushort(__float2half(cen[1].z)) << 16);
        pk4.w = (uint)__half_as_ushort(__float2half(cen[0].w)) |
                ((uint)__half_as_ushort(__float2half(cen[1].w)) << 16);
        *(uint4*)(xTp + ((size_t)(bg * 8 + pc)) * HW + row * IMG_W + cb * 4) = pk4;
    }

#pragma unroll
    for (int d = 32; d; d >>= 1) {
        s1o += __shfl_down(s1o, d);
        s2o += __shfl_down(s2o, d);
        s1m += __shfl_down(s1m, d);
        s2m += __shfl_down(s2m, d);
    }
    __shared__ float red[4][4];
    if ((t & 63) == 0) {
        int w = t >> 6;
        red[w][0] = s1o; red[w][1] = s2o; red[w][2] = s1m; red[w][3] = s2m;
    }
    __syncthreads();
    if (t < 4) {
        float v = red[0][t] + red[1][t] + red[2][t] + red[3][t];
        partial[(size_t)bid * 4 + t] = v;
    }
}

// ---------------------------------------------------------------------------
// k_finfold: one block per sample. Phase 1: reduce partials -> GN affine in
// LDS. Phase 2: emit GN-folded pw-GEMM MFMA B-fragments + dconst.
__global__ __launch_bounds__(256) void k_finfold(const float* __restrict__ partial,
                      const float* __restrict__ gog, const float* __restrict__ gob,
                      const float* __restrict__ gmg, const float* __restrict__ gmb,
                      const float* __restrict__ wT,
                      const float* __restrict__ bpo,
                      const float* __restrict__ bpm,
                      uint2* __restrict__ wbo,
                      uint2* __restrict__ wbm,
                      float* __restrict__ dconst) {
    __shared__ float adsh[256];
    int b = blockIdx.x, t = threadIdx.x;
    {
        const float4* pp = (const float4*)partial + (size_t)b * 512;
        float4 s = make_float4(0.f, 0.f, 0.f, 0.f);
#pragma unroll
        for (int i = 0; i < 2; ++i) {
            float4 v = pp[t + i * 256];
            s.x += v.x; s.y += v.y; s.z += v.z; s.w += v.w;
        }
#pragma unroll
        for (int d = 32; d; d >>= 1) {
            s.x += __shfl_down(s.x, d);
            s.y += __shfl_down(s.y, d);
            s.z += __shfl_down(s.z, d);
            s.w += __shfl_down(s.w, d);
        }
        __shared__ float red[4][4];
        if ((t & 63) == 0) {
            int w = t >> 6;
            red[w][0] = s.x; red[w][1] = s.y; red[w][2] = s.z; red[w][3] = s.w;
        }
        __syncthreads();
        if (t < 64) {
            float s1o = red[0][0] + red[1][0] + red[2][0] + red[3][0];
            float s2o = red[0][1] + red[1][1] + red[2][1] + red[3][1];
            float s1m = red[0][2] + red[1][2] + red[2][2] + red[3][2];
            float s2m = red[0][3] + red[1][3] + red[2][3] + red[3][3];
            int c = t;
            const float invN = 1.f / 1048576.f;
            float m_o = s1o * invN;
            float v_o = s2o * invN - m_o * m_o;
            float i_o = rsqrtf(v_o + 1e-5f);
            float m_m = s1m * invN;
            float v_m = s2m * invN - m_m * m_m;
            float i_m = rsqrtf(v_m + 1e-5f);
            adsh[c * 4 + 0] = i_o * gog[c];
            adsh[c * 4 + 1] = gob[c] - m_o * (i_o * gog[c]);
            adsh[c * 4 + 2] = i_m * gmg[c];
            adsh[c * 4 + 3] = gmb[c] - m_m * (i_m * gmg[c]);
        }
        __syncthreads();
    }
    for (int i = t; i < 2048; i += 256) {       // off frags
        int lane = i & 63;
        int f = i >> 6;
        int g = f >> 3, kk = (f >> 1) & 3, nf = f & 1;
        int n = lane & 15, q = lane >> 4;
        int out = nf * 16 + n;
        union { ushort h[4]; uint2 u; } pk;
#pragma unroll
        for (int jj = 0; jj < 4; ++jj) {
            int ch = kk * 16 + 4 * q + jj;
            float w = (out < 18) ? adsh[ch * 4 + 0] * wT[ch * 108 + g * 18 + out] : 0.f;
            pk.h[jj] = __half_as_ushort(__float2half(w));
        }
        wbo[((size_t)(b * 4) + g) * 8 * 64 + (size_t)(kk * 2 + nf) * 64 + lane] = pk.u;
    }
    for (int i = t; i < 1024; i += 256) {       // mask frags
        int lane = i & 63;
        int f = i >> 6;
        int g = f >> 2, kk = f & 3;
        int n = lane & 15, q = lane >> 4;
        union { ushort h[4]; uint2 u; } pk;
#pragma unroll
        for (int jj = 0; jj < 4; ++jj) {
            int ch = kk * 16 + 4 * q + jj;
            float w = (n < 9) ? adsh[ch * 4 + 2] * wT[ch * 108 + 72 + g * 9 + n] : 0.f;
            pk.h[jj] = __half_as_ushort(__float2half(w));
        }
        wbm[((size_t)(b * 4) + g) * 4 * 64 + (size_t)kk * 64 + lane] = pk.u;
    }
    if (t < 108) {
        float s = (t < 72) ? bpo[t] : bpm[t - 72];
        for (int c = 0; c < 64; ++c) {
            float d = (t < 72) ? adsh[c * 4 + 1] : adsh[c * 4 + 3];
            s = fmaf(d, wT[c * 108 + t], s);
        }
        dconst[b * 108 + t] = s;
    }
}

// ---------------------------------------------------------------------------
// k_gthf: FUSED MFMA pw-GEMM + softmax + LDS-staged bilinear gather + MFMA.
// R17 body; staging now reads 8 coalesced plane uints (same bytes -> same
// xsA/xsB LDS layout; gather loop unchanged).
__global__ __launch_bounds__(256, 4) void k_gthf(const uint2* __restrict__ t2p,
                                                 const uint2* __restrict__ wbo,
                                                 const uint2* __restrict__ wbm,
                                                 const float* __restrict__ dconst,
                                                 const uint* __restrict__ xTp,
                                                 const uint2* __restrict__ wb,
                                                 const float* __restrict__ bias,
                                                 float* __restrict__ out) {
    __shared__ union SMem {
        struct {
            uint4 xsA[506];     // 22 rows x stride 23, ch 0-7
            uint4 xsB[506];     // ch 8-15
            uint  slab[5120];   // 4 waves x [64 px][20 uint] (A/D/shv alias)
        } s;
        float shout[4864];      // 256 px x stride 19 (aliased, post-barrier)
    } sm;

    int tid = threadIdx.x;
    int bid = blockIdx.x;
    int bg = bid >> 6;                      // slice-major: g-variants same XCD
    int tile = bid & 63;
    int tr = tile >> 3, tc = tile & 7;
    int r0 = tr * 16, c0 = tc * 16;
    int g = bg & 3, b = bg >> 2;
    int wr0 = r0 - 3, wc0 = c0 - 3;

    const uint* xgp = xTp + (size_t)bg * 8 * HW;

#pragma unroll
    for (int it = 0; it < 2; ++it) {
        int idx = tid + it * 256;
        if (idx < 484) {
            int ly = idx / 22, lx = idx - ly * 22;
            int sr = wr0 + ly; sr = sr < 0 ? 0 : (sr > 127 ? 127 : sr);
            int sc = wc0 + lx; sc = sc < 0 ? 0 : (sc > 127 ? 127 : sc);
            int po = sr * IMG_W + sc;
            uint u0 = xgp[0 * HW + po], u1 = xgp[1 * HW + po];
            uint u2 = xgp[2 * HW + po], u3 = xgp[3 * HW + po];
            uint u4 = xgp[4 * HW + po], u5 = xgp[5 * HW + po];
            uint u6 = xgp[6 * HW + po], u7 = xgp[7 * HW + po];
            sm.s.xsA[ly * 23 + lx] = make_uint4(u0, u1, u2, u3);
            sm.s.xsB[ly * 23 + lx] = make_uint4(u4, u5, u6, u7);
        }
    }

    int row = r0 + (tid >> 4), col = c0 + (tid & 15);
    int p = row * IMG_W + col;
    int lane = tid & 63, wv = tid >> 6;
    int m_idx = lane & 15, q_idx = lane >> 4;

    union BU { uint2 u; f16x4 h; };

    const uint2* wboP = wbo + ((size_t)(b * 4) + g) * 8 * 64 + lane;
    const uint2* wbmP = wbm + ((size_t)(b * 4) + g) * 4 * 64 + lane;
    f16x4 bO[8], bM[4];
#pragma unroll
    for (int i = 0; i < 8; ++i) { BU t; t.u = wboP[i * 64]; bO[i] = t.h; }
#pragma unroll
    for (int i = 0; i < 4; ++i) { BU t; t.u = wbmP[i * 64]; bM[i] = t.h; }

    const uint2* wbp = wb + (size_t)(g * 9) * 64 + lane;
    f16x4 bfr[9];
#pragma unroll
    for (int k = 0; k < 9; ++k) { BU t; t.u = wbp[k * 64]; bfr[k] = t.h; }

    uint* aslab = sm.s.slab + wv * 1280;        // [64 px][20 uint]
    const uint2* tp = t2p + (size_t)b * 32 * HW + p;

    f32x4 accO0[4], accO1[4], accM[4];
#pragma unroll
    for (int s = 0; s < 4; ++s) {
        accO0[s] = (f32x4){0.f, 0.f, 0.f, 0.f};
        accO1[s] = (f32x4){0.f, 0.f, 0.f, 0.f};
        accM[s]  = (f32x4){0.f, 0.f, 0.f, 0.f};
    }

#pragma unroll
    for (int kk = 0; kk < 4; ++kk) {
        uint2 v[8];
#pragma unroll
        for (int j = 0; j < 8; ++j) v[j] = tp[(size_t)(kk * 8 + j) * HW];
        uint* rowp = aslab + lane * 20;
        ((uint4*)rowp)[0] = make_uint4(v[0].x, v[1].x, v[2].x, v[3].x);
        ((uint4*)rowp)[1] = make_uint4(v[4].x, v[5].x, v[6].x, v[7].x);
        ((uint4*)(rowp + 8))[0] = make_uint4(v[0].y, v[1].y, v[2].y, v[3].y);
        ((uint4*)(rowp + 8))[1] = make_uint4(v[4].y, v[5].y, v[6].y, v[7].y);
#pragma unroll
        for (int s = 0; s < 4; ++s) {
            const uint* pr = aslab + (s * 16 + m_idx) * 20 + 2 * q_idx;
            BU ao, am;
            ao.u = *(const uint2*)pr;
            am.u = *(const uint2*)(pr + 8);
            accO0[s] = __builtin_amdgcn_mfma_f32_16x16x16f16(ao.h, bO[kk * 2 + 0], accO0[s], 0, 0, 0);
            accO1[s] = __builtin_amdgcn_mfma_f32_16x16x16f16(ao.h, bO[kk * 2 + 1], accO1[s], 0, 0, 0);
            accM[s]  = __builtin_amdgcn_mfma_f32_16x16x16f16(am.h, bM[kk], accM[s], 0, 0, 0);
        }
    }

    const float* dc = dconst + b * 108;

#pragma unroll
    for (int s = 0; s < 4; ++s)
#pragma unroll
        for (int j = 0; j < 4; ++j) {
            int px = s * 16 + 4 * q_idx + j;
            union { __half2 h2; uint u; } pk;
            pk.h2 = __halves2half2(__float2half(accO0[s][j]),
                                   __float2half(accO1[s][j]));
            aslab[px * 20 + m_idx] = pk.u;
        }
    float facc[18];
    {
        const uint4* dr = (const uint4*)(aslab + lane * 20);
        uint4 d0 = dr[0], d1 = dr[1], d2 = dr[2], d3 = dr[3];
        uint du[16] = {d0.x, d0.y, d0.z, d0.w, d1.x, d1.y, d1.z, d1.w,
                       d2.x, d2.y, d2.z, d2.w, d3.x, d3.y, d3.z, d3.w};
        union { uint u; __half2 h2; } cv;
#pragma unroll
        for (int i = 0; i < 16; ++i) {
            cv.u = du[i];
            float2 f = __half22float2(cv.h2);
            facc[i] = f.x + dc[g * 18 + i];
            if (i < 2) facc[16 + i] = f.y + dc[g * 18 + 16 + i];
        }
    }

    {
        float* fsl = (float*)aslab;
#pragma unroll
        for (int s = 0; s < 4; ++s)
#pragma unroll
            for (int j = 0; j < 4; ++j) {
                int px = s * 16 + 4 * q_idx + j;
                fsl[px * 20 + m_idx] = accM[s][j];
            }
        float macc[9];
#pragma unroll
        for (int k = 0; k < 9; ++k) macc[k] = fsl[lane * 20 + k] + dc[72 + g * 9 + k];
        float mx = macc[0];
#pragma unroll
        for (int k = 1; k < 9; ++k) mx = fmaxf(mx, macc[k]);
        float ssum = 0.f;
#pragma unroll
        for (int k = 0; k < 9; ++k) {
            float e = __expf(macc[k] - mx);
            macc[k] = e;
            ssum += e;
        }
        float inv = 1.f / ssum;
#pragma unroll
        for (int k = 0; k < 9; ++k) macc[k] *= inv;

        __syncthreads();    // staging visible to all; slab GEMM data consumed

        uint4* shvw = (uint4*)aslab + lane * 3;
        const _Float16* shvh = (const _Float16*)aslab;

        f32x4 acc[4];
#pragma unroll
        for (int s = 0; s < 4; ++s) acc[s] = (f32x4){0.f, 0.f, 0.f, 0.f};

#pragma unroll
        for (int k = 0; k < 9; ++k) {
            float mk = macc[k];
            float py = (float)(row + k / 3 - 1) + facc[k * 2 + 0];
            float px = (float)(col + k % 3 - 1) + facc[k * 2 + 1];
            float y0f = floorf(py), x0f = floorf(px);
            float wy = py - y0f, wx = px - x0f;
            int iy0 = (int)y0f, ix0 = (int)x0f;
            int iy1 = iy0 + 1, ix1 = ix0 + 1;
            float fy0 = (iy0 >= 0 && iy0 < IMG_H) ? (1.f - wy) : 0.f;
            float fy1 = (iy1 >= 0 && iy1 < IMG_H) ? wy : 0.f;
            float fx0 = (ix0 >= 0 && ix0 < IMG_W) ? (1.f - wx) : 0.f;
            float fx1 = (ix1 >= 0 && ix1 < IMG_W) ? wx : 0.f;
            __half2 f00h = __float2half2_rn(fy0 * fx0 * mk);
            __half2 f01h = __float2half2_rn(fy0 * fx1 * mk);
            __half2 f10h = __float2half2_rn(fy1 * fx0 * mk);
            __half2 f11h = __float2half2_rn(fy1 * fx1 * mk);
            int ly0 = iy0 - wr0; ly0 = ly0 < 0 ? 0 : (ly0 > 21 ? 21 : ly0);
            int ly1 = iy1 - wr0; ly1 = ly1 < 0 ? 0 : (ly1 > 21 ? 21 : ly1);
            int lx0 = ix0 - wc0; lx0 = lx0 < 0 ? 0 : (lx0 > 21 ? 21 : lx0);
            int lx1 = ix1 - wc0; lx1 = lx1 < 0 ? 0 : (lx1 > 21 ? 21 : lx1);
            int i00 = ly0 * 23 + lx0, i01 = ly0 * 23 + lx1;
            int i10 = ly1 * 23 + lx0, i11 = ly1 * 23 + lx1;
            union Q8 { uint4 u[2]; __half2 h2[8]; };
            Q8 q00, q01, q10, q11;
            q00.u[0] = sm.s.xsA[i00]; q00.u[1] = sm.s.xsB[i00];
            q01.u[0] = sm.s.xsA[i01]; q01.u[1] = sm.s.xsB[i01];
            q10.u[0] = sm.s.xsA[i10]; q10.u[1] = sm.s.xsB[i10];
            q11.u[0] = sm.s.xsA[i11]; q11.u[1] = sm.s.xsB[i11];
            union V8 { __half2 h2[4]; uint4 u; };
            V8 pa, pb;
#pragma unroll
            for (int i = 0; i < 4; ++i) {
                __half2 vh = __hmul2(f00h, q00.h2[i]);
                vh = __hfma2(f01h, q01.h2[i], vh);
                vh = __hfma2(f10h, q10.h2[i], vh);
                vh = __hfma2(f11h, q11.h2[i], vh);
                pa.h2[i] = vh;
            }
#pragma unroll
            for (int i = 4; i < 8; ++i) {
                __half2 vh = __hmul2(f00h, q00.h2[i]);
                vh = __hfma2(f01h, q01.h2[i], vh);
                vh = __hfma2(f10h, q10.h2[i], vh);
                vh = __hfma2(f11h, q11.h2[i], vh);
                pb.h2[i - 4] = vh;
            }
            shvw[0] = pa.u;
            shvw[1] = pb.u;
#pragma unroll
            for (int s = 0; s < 4; ++s) {
                f16x4 af = *(const f16x4*)(shvh +
                            ((size_t)(s * 16 + m_idx)) * 24 + q_idx * 4);
                acc[s] = __builtin_amdgcn_mfma_f32_16x16x16f16(af, bfr[k], acc[s], 0, 0, 0);
            }
        }

        __syncthreads();   // all waves done with xs window before aliasing shout

#pragma unroll
        for (int s = 0; s < 4; ++s)
#pragma unroll
            for (int j = 0; j < 4; ++j)
                sm.shout[(wv * 64 + s * 16 + 4 * q_idx + j) * 19 + m_idx] = acc[s][j];

        float* outp = out + ((size_t)b * 64 + g * 16) * HW + p;
#pragma unroll
        for (int o = 0; o < 16; ++o)
            outp[(size_t)o * HW] = sm.shout[tid * 19 + o] + bias[g * 16 + o];
    }
}

// ---------------------------------------------------------------------------
extern "C" void kernel_launch(void* const* d_in, const int* in_sizes, int n_in,
                              void* d_out, int out_size, void* d_ws, size_t ws_size,
                              hipStream_t stream) {
    const float* x        = (const float*)d_in[0];
    const float* w_dw_off = (const float*)d_in[1];
    const float* b_dw_off = (const float*)d_in[2];
    const float* gn_off_g = (const float*)d_in[3];
    const float* gn_off_b = (const float*)d_in[4];
    const float* w_pw_off = (const float*)d_in[5];
    const float* b_pw_off = (const float*)d_in[6];
    const float* w_dw_m   = (const float*)d_in[7];
    const float* b_dw_m   = (const float*)d_in[8];
    const float* gn_m_g   = (const float*)d_in[9];
    const float* gn_m_b   = (const float*)d_in[10];
    const float* w_pw_m   = (const float*)d_in[11];
    const float* b_pw_m   = (const float*)d_in[12];
    const float* weight   = (const float*)d_in[13];
    const float* bias     = (const float*)d_in[14];

    float* ws = (float*)d_ws;
    uint2* t2p    = (uint2*)(ws + OFF_T2);
    uint* xTp     = (uint*)(ws + OFF_XT);
    float* wT     = ws + OFF_WT;
    float* part   = ws + OFF_PART;
    const uint2* wb = (const uint2*)(ws + OFF_WB);
    const uint* wdw2 = (const uint*)(ws + OFF_WDW2);
    uint2* wbo    = (uint2*)(ws + OFF_WBO);
    uint2* wbm    = (uint2*)(ws + OFF_WBM);
    float* dconst = ws + OFF_DC;

    k_prep<<<50, 256, 0, stream>>>(w_pw_off, w_pw_m, weight, w_dw_off, w_dw_m, ws);
    k_dw<<<4096, 256, 0, stream>>>(x, b_dw_off, b_dw_m, wdw2, t2p, xTp, part);
    k_finfold<<<8, 256, 0, stream>>>(part, gn_off_g, gn_off_b, gn_m_g, gn_m_b,
                                     wT, b_pw_off, b_pw_m, wbo, wbm, dconst);
    k_gthf<<<2048, 256, 0, stream>>>(t2p, wbo, wbm, dconst, xTp, wb, bias, (float*)d_out);
}